// Round 15
// baseline (294.401 us; speedup 1.0000x reference)
//
#include <hip/hip_runtime.h>
#include <hip/hip_fp16.h>
#include <math.h>

// HOG multi-scale feature extractor for 28x28 images. v15 (base v10):
// Measured: write-time (~88us) and compute-time (~95us) were SUMMING, not
// overlapping (E pinned behind the last barrier). Fix: forward emission --
// each norm-task thread stores its own output run right after computing its
// norm factors (all task output runs are 16B-aligned, verified). The inverse
// map table, nrm[] LDS array, and one barrier phase are eliminated.
//  - A/B/C identical to v10 (185us, reproducible).
//  - D': norm (2-pass streaming) + 3rd compile-time-unrolled pass emits
//    BINS float4s per task directly to global. Flat part emitted after.
//  - LDS: img 3.1K + ma 3.1K (half2) + hist 11.2K = 17.4KB -> 8 blocks/CU.

constexpr int NPIX = 784;
constexpr int FEAT = 8296;            // 784 + 1152 + 2304 + 4056
constexpr int PB4 = 10, PB3 = 10, PB2 = 8;  // padded cell strides (even)
constexpr int O4P = 0;                // 49 cells  (7x7,  8 bins)
constexpr int O3P = 490;              // 81 cells  (9x9,  9 bins)
constexpr int O2P = 1300;             // 196 cells (14x14, 6 bins)
constexpr int HIST_TOT = 2868;        // 1300 + 196*8
constexpr int NTASK = 269;            // 36 + 64 + 169 block-norm tasks
constexpr int NCELL = 49 + 81 + 196;  // 326 histogram cells

__global__ __launch_bounds__(256)
void setup_kernel(const float* __restrict__ fmean,
                  const float* __restrict__ fstd,
                  float2* __restrict__ msr) {
    int i = blockIdx.x * 256 + threadIdx.x;
    if (i < FEAT)
        msr[i] = make_float2(fmean[i], 1.0f / fstd[i]);
}

// branchless orientation in degrees == (atan2(gy,gx)*180/pi + 180) mod 180
__device__ __forceinline__ float orient_deg(float gy, float gx) {
    float ax = fabsf(gx), ay = fabsf(gy);
    float mn = fminf(ax, ay), mx = fmaxf(ax, ay);
    float r = __fdividef(mn, mx + 1e-37f);          // [0,1]
    float a = r * r;                                 // A&S 4.4.49, |err|<=1e-5
    float th = ((((0.0208351f * a - 0.0851330f) * a + 0.1801410f) * a
                 - 0.3302995f) * a + 0.9998660f) * r;
    th *= 57.29577951308232f;                        // rad -> deg, [0,45]
    if (ay > ax) th = 90.0f - th;                    // [0,90]
    bool neg = ((__float_as_uint(gx) ^ __float_as_uint(gy)) >> 31) != 0;
    float o = neg ? 180.0f - th : th;
    return (o >= 180.0f) ? 0.0f : o;                 // in [0,180)
}

__device__ __forceinline__ float ldimg(const float* img, int y, int x) {
    return (y >= 0 && y < 28 && x >= 0 && x < 28) ? img[y * 28 + x] : 0.0f;
}

// 2-pass streaming L2-hys norm + 3rd pass forward emission (compile-time
// unrolled; every hist index is qb[q]+j with q,j constants).
template <int BINS, bool USE_TABLE>
__device__ __forceinline__ void norm_emit(const float* __restrict__ hist,
                                          int c00, int Wc, int pb,
                                          float4* __restrict__ outp,
                                          const float4* __restrict__ msr4,
                                          const float* __restrict__ fmean,
                                          const float* __restrict__ fstd,
                                          int gi4) {
    int qb[4] = {c00, c00 + pb, c00 + Wc * pb, c00 + (Wc + 1) * pb};
    float s = 1e-6f;
    #pragma unroll
    for (int q = 0; q < 4; ++q) {
        #pragma unroll
        for (int j = 0; j < BINS / 2; ++j) {
            float2 v = *reinterpret_cast<const float2*>(&hist[qb[q] + 2 * j]);
            s += v.x * v.x + v.y * v.y;
        }
        if (BINS & 1) {
            float v = hist[qb[q] + BINS - 1];
            s += v * v;
        }
    }
    float ninv = 1.0f / sqrtf(s);
    float s2 = 1e-6f;
    #pragma unroll
    for (int q = 0; q < 4; ++q) {
        #pragma unroll
        for (int j = 0; j < BINS / 2; ++j) {
            float2 v = *reinterpret_cast<const float2*>(&hist[qb[q] + 2 * j]);
            float c0 = fminf(v.x * ninv, 0.2f);
            float c1 = fminf(v.y * ninv, 0.2f);
            s2 += c0 * c0 + c1 * c1;
        }
        if (BINS & 1) {
            float c = fminf(hist[qb[q] + BINS - 1] * ninv, 0.2f);
            s2 += c * c;
        }
    }
    float n2inv = 1.0f / sqrtf(s2);
    // pass 3: emit 4*BINS values as BINS float4s (run is 16B-aligned)
    #pragma unroll
    for (int f = 0; f < BINS; ++f) {
        float v[4];
        #pragma unroll
        for (int e = 0; e < 4; ++e) {
            constexpr int dummy = 0; (void)dummy;
            int pos = 4 * f + e;               // compile-time
            int q = pos / BINS, j = pos - q * BINS;
            v[e] = hist[qb[q] + j];
        }
        float4 r;
        if (USE_TABLE) {
            float4 p0 = msr4[(gi4 + f) * 2], p1 = msr4[(gi4 + f) * 2 + 1];
            r.x = (fminf(v[0] * ninv, 0.2f) * n2inv - p0.x) * p0.y;
            r.y = (fminf(v[1] * ninv, 0.2f) * n2inv - p0.z) * p0.w;
            r.z = (fminf(v[2] * ninv, 0.2f) * n2inv - p1.x) * p1.y;
            r.w = (fminf(v[3] * ninv, 0.2f) * n2inv - p1.z) * p1.w;
        } else {
            int i = (gi4 + f) * 4;
            r.x = (fminf(v[0] * ninv, 0.2f) * n2inv - fmean[i])     / fstd[i];
            r.y = (fminf(v[1] * ninv, 0.2f) * n2inv - fmean[i + 1]) / fstd[i + 1];
            r.z = (fminf(v[2] * ninv, 0.2f) * n2inv - fmean[i + 2]) / fstd[i + 2];
            r.w = (fminf(v[3] * ninv, 0.2f) * n2inv - fmean[i + 3]) / fstd[i + 3];
        }
        outp[gi4 + f] = r;
    }
}

template <bool USE_TABLE>
__global__ __launch_bounds__(256)
void hog_kernel(const float* __restrict__ x,
                const float* __restrict__ fmean,
                const float* __restrict__ fstd,
                const float2* __restrict__ msr,
                float* __restrict__ out) {
    __shared__ __align__(16) float img[NPIX];
    __shared__ __align__(16) __half2 ma[NPIX];  // (mag, ang) packed f16
    __shared__ __align__(16) float hist[HIST_TOT];

    const int b = blockIdx.x;
    const int tid = threadIdx.x;
    const float* xb = x + (size_t)b * NPIX;
    float4* outp = reinterpret_cast<float4*>(out + (size_t)b * FEAT);
    const float4* msr4 = reinterpret_cast<const float4*>(msr);

    // ---- A: load image (coalesced float4) + zero hist (float4) ----
    for (int i = tid; i < NPIX / 4; i += 256)
        reinterpret_cast<float4*>(img)[i] =
            reinterpret_cast<const float4*>(xb)[i];
    for (int i = tid; i < HIST_TOT / 4; i += 256)
        reinterpret_cast<float4*>(hist)[i] = make_float4(0.f, 0.f, 0.f, 0.f);
    __syncthreads();

    // ---- B: pixel-parallel Sobel + (mag, ang) -> half2 LDS ----
    for (int p = tid; p < NPIX; p += 256) {
        int y = p / 28, xx = p - (p / 28) * 28;
        float a00 = ldimg(img, y - 1, xx - 1);
        float a01 = ldimg(img, y - 1, xx);
        float a02 = ldimg(img, y - 1, xx + 1);
        float a10 = ldimg(img, y,     xx - 1);
        float a12 = ldimg(img, y,     xx + 1);
        float a20 = ldimg(img, y + 1, xx - 1);
        float a21 = ldimg(img, y + 1, xx);
        float a22 = ldimg(img, y + 1, xx + 1);
        float gxv = (a00 + 2.0f * a10 + a20 - a02 - 2.0f * a12 - a22) * 0.25f;
        float gyv = (a00 + 2.0f * a01 + a02 - a20 - 2.0f * a21 - a22) * 0.25f;
        float mag = sqrtf(gxv * gxv + gyv * gyv + 1e-6f);
        ma[p] = __floats2half2_rn(mag, orient_deg(gyv, gxv));
    }
    __syncthreads();

    // ---- C: cell-parallel exclusive RMW, wrap slot + adjacent pair.
    //      Identity task order (scale-sorted): uniform trip count per wave.
    for (int t = tid; t < NCELL; t += 256) {
        int base, y0, x0, ny, nx, bins;
        float invbw;                       // bins / 180
        if (t < 49) {                      // cell=4, bins=8, 4x4 px
            int cy = t / 7, cx = t - cy * 7;
            y0 = cy * 4; x0 = cx * 4; ny = 4; nx = 4;
            bins = 8; invbw = 8.0f / 180.0f;
            base = O4P + t * PB4;
        } else if (t < 130) {              // cell=3, bins=9, 3-4 x 3-4 px
            int k = t - 49;
            int cy = k / 9, cx = k - cy * 9;
            y0 = cy * 3; x0 = cx * 3;
            ny = (cy == 8) ? 4 : 3; nx = (cx == 8) ? 4 : 3;
            bins = 9; invbw = 9.0f / 180.0f;
            base = O3P + k * PB3;
        } else {                           // cell=2, bins=6, 2x2 px
            int k = t - 130;
            int cy = k / 14, cx = k - cy * 14;
            y0 = cy * 2; x0 = cx * 2; ny = 2; nx = 2;
            bins = 6; invbw = 6.0f / 180.0f;
            base = O2P + k * PB2;
        }
        for (int iy = 0; iy < ny; ++iy) {
            int row = (y0 + iy) * 28 + x0;
            for (int ix = 0; ix < nx; ++ix) {
                float2 m = __half22float2(ma[row + ix]);
                float tb = m.y * invbw;            // in [0, bins]
                int b0 = (int)tb;
                if (b0 > bins - 1) b0 = bins - 1;  // f16-edge guard (ang->180)
                float frac = tb - (float)b0;
                float w1 = m.x * frac;
                float w0 = m.x - w1;
                int a = base + b0;                 // b1==bins -> wrap slot
                float h0 = hist[a];
                float h1 = hist[a + 1];            // ds_read2_b32
                hist[a]     = h0 + w0;
                hist[a + 1] = h1 + w1;             // ds_write2_b32
            }
        }
        hist[base] += hist[base + bins];           // fold wrap slot into bin 0
    }
    __syncthreads();

    // ---- D': per-task norm + FORWARD emission (no map, no nrm LDS) ----
    for (int t = tid; t < NTASK; t += 256) {
        if (t < 36) {
            int by = t / 6, bx = t - (t / 6) * 6;
            norm_emit<8, USE_TABLE>(hist, O4P + (by * 7 + bx) * PB4, 7, PB4,
                                    outp, msr4, fmean, fstd, 196 + t * 8);
        } else if (t < 100) {
            int k = t - 36;
            norm_emit<9, USE_TABLE>(hist, O3P + ((k >> 3) * 9 + (k & 7)) * PB3,
                                    9, PB3, outp, msr4, fmean, fstd,
                                    484 + k * 9);
        } else {
            int k = t - 100;
            int by = k / 13, bx = k - by * 13;
            norm_emit<6, USE_TABLE>(hist, O2P + (by * 14 + bx) * PB2, 14, PB2,
                                    outp, msr4, fmean, fstd, 1060 + k * 6);
        }
    }

    // ---- flat part (img stable since A; no barrier needed) ----
    for (int i4 = tid; i4 < NPIX / 4; i4 += 256) {
        float4 v = reinterpret_cast<const float4*>(img)[i4];
        float4 r;
        if (USE_TABLE) {
            float4 p0 = msr4[i4 * 2], p1 = msr4[i4 * 2 + 1];
            r.x = (v.x - p0.x) * p0.y;  r.y = (v.y - p0.z) * p0.w;
            r.z = (v.z - p1.x) * p1.y;  r.w = (v.w - p1.z) * p1.w;
        } else {
            int i = i4 * 4;
            r.x = (v.x - fmean[i])     / fstd[i];
            r.y = (v.y - fmean[i + 1]) / fstd[i + 1];
            r.z = (v.z - fmean[i + 2]) / fstd[i + 2];
            r.w = (v.w - fmean[i + 3]) / fstd[i + 3];
        }
        outp[i4] = r;
    }
}

extern "C" void kernel_launch(void* const* d_in, const int* in_sizes, int n_in,
                              void* d_out, int out_size, void* d_ws, size_t ws_size,
                              hipStream_t stream) {
    const float* x     = (const float*)d_in[0];
    const float* fmean = (const float*)d_in[1];
    const float* fstd  = (const float*)d_in[2];
    float* out = (float*)d_out;
    int B = in_sizes[0] / NPIX;

    const size_t msr_bytes = (size_t)FEAT * sizeof(float2);   // 66368
    if (ws_size >= msr_bytes) {
        float2* msr = (float2*)d_ws;
        hipLaunchKernelGGL(setup_kernel, dim3((FEAT + 255) / 256), dim3(256),
                           0, stream, fmean, fstd, msr);
        hipLaunchKernelGGL(hog_kernel<true>, dim3(B), dim3(256), 0, stream,
                           x, fmean, fstd, msr, out);
    } else {
        hipLaunchKernelGGL(hog_kernel<false>, dim3(B), dim3(256), 0, stream,
                           x, fmean, fstd, nullptr, out);
    }
}

// Round 16
// 254.791 us; speedup vs baseline: 1.1555x; 1.1555x over previous
//
#include <hip/hip_runtime.h>
#include <hip/hip_fp16.h>
#include <math.h>

// HOG multi-scale feature extractor for 28x28 images. v16:
// Software pipeline across NIMG=8 images per block. v10's phases kept
// verbatim; hist/nrm double-buffered; E_hog(k) (v10's coalesced epilogue,
// unchanged) issues in the same phase as A(k+1)'s loads so its stores drain
// under the next image's B/C/D compute (write/compute overlap; v15's lesson:
// keep writes coalesced, v14's lesson: compute+write were summing).
// Flat-part emit moved into phase D (img stable there). nrm as half2
// (v13-proven). LDS 31.4KB -> 5 blocks/CU.

constexpr int NPIX = 784;
constexpr int FEAT = 8296;            // 784 + 1152 + 2304 + 4056
constexpr int PB4 = 10, PB3 = 10, PB2 = 8;  // padded cell strides (even)
constexpr int O4P = 0;                // 49 cells  (7x7,  8 bins)
constexpr int O3P = 490;              // 81 cells  (9x9,  9 bins)
constexpr int O2P = 1300;             // 196 cells (14x14, 6 bins)
constexpr int HIST_TOT = 2868;        // 1300 + 196*8
constexpr int NTASK = 269;            // 36 + 64 + 169 block-norm tasks
constexpr int NHOG = FEAT - NPIX;     // 7512 table entries
constexpr int NCELL = 49 + 81 + 196;  // 326 histogram cells

// ---- output index i in [784,8296) -> packed (task<<12)|hist_idx ----
__device__ __forceinline__ int feat_map(int i) {
    int task, h;
    if (i < 1936) {                    // h4: 36 tasks x 4q x 8 bins
        int k = i - 784;
        int t = k >> 5, r = k & 31;
        int q = r >> 3, j = r & 7;
        int by = t / 6, bx = t - by * 6;
        h = O4P + ((by + (q >> 1)) * 7 + bx + (q & 1)) * PB4 + j;
        task = t;
    } else if (i < 4240) {             // h3: 64 tasks x 4q x 9 bins
        int k = i - 1936;
        int t = k / 36, r = k - t * 36;
        int q = r / 9,  j = r - q * 9;
        int by = t >> 3, bx = t & 7;
        h = O3P + ((by + (q >> 1)) * 9 + bx + (q & 1)) * PB3 + j;
        task = 36 + t;
    } else {                           // h2: 169 tasks x 4q x 6 bins
        int k = i - 4240;
        int t = k / 24, r = k - t * 24;
        int q = r / 6,  j = r - q * 6;
        int by = t / 13, bx = t - by * 13;
        h = O2P + ((by + (q >> 1)) * 14 + bx + (q & 1)) * PB2 + j;
        task = 100 + t;
    }
    return (task << 12) | h;           // h < 2868 fits in 12 bits
}

__global__ __launch_bounds__(256)
void setup_kernel(const float* __restrict__ fmean,
                  const float* __restrict__ fstd,
                  float2* __restrict__ msr, int* __restrict__ map) {
    int i = blockIdx.x * 256 + threadIdx.x;
    if (i < FEAT) {
        msr[i] = make_float2(fmean[i], 1.0f / fstd[i]);
        if (i >= NPIX) map[i - NPIX] = feat_map(i);
    }
}

// branchless orientation in degrees == (atan2(gy,gx)*180/pi + 180) mod 180
__device__ __forceinline__ float orient_deg(float gy, float gx) {
    float ax = fabsf(gx), ay = fabsf(gy);
    float mn = fminf(ax, ay), mx = fmaxf(ax, ay);
    float r = __fdividef(mn, mx + 1e-37f);          // [0,1]
    float a = r * r;                                 // A&S 4.4.49, |err|<=1e-5
    float th = ((((0.0208351f * a - 0.0851330f) * a + 0.1801410f) * a
                 - 0.3302995f) * a + 0.9998660f) * r;
    th *= 57.29577951308232f;                        // rad -> deg, [0,45]
    if (ay > ax) th = 90.0f - th;                    // [0,90]
    bool neg = ((__float_as_uint(gx) ^ __float_as_uint(gy)) >> 31) != 0;
    float o = neg ? 180.0f - th : th;
    return (o >= 180.0f) ? 0.0f : o;                 // in [0,180)
}

__device__ __forceinline__ float ldimg(const float* img, int y, int x) {
    return (y >= 0 && y < 28 && x >= 0 && x < 28) ? img[y * 28 + x] : 0.0f;
}

// ---------------- v10 phase bodies, parameterized by buffers ----------------

__device__ __forceinline__ void phaseA(const float* __restrict__ xb,
                                       float* __restrict__ img,
                                       float* __restrict__ histb, int tid) {
    for (int i = tid; i < NPIX / 4; i += 256)
        reinterpret_cast<float4*>(img)[i] =
            reinterpret_cast<const float4*>(xb)[i];
    for (int i = tid; i < HIST_TOT / 4; i += 256)
        reinterpret_cast<float4*>(histb)[i] = make_float4(0.f, 0.f, 0.f, 0.f);
}

__device__ __forceinline__ void phaseB(const float* __restrict__ img,
                                       __half2* __restrict__ ma, int tid) {
    for (int p = tid; p < NPIX; p += 256) {
        int y = p / 28, xx = p - (p / 28) * 28;
        float a00 = ldimg(img, y - 1, xx - 1);
        float a01 = ldimg(img, y - 1, xx);
        float a02 = ldimg(img, y - 1, xx + 1);
        float a10 = ldimg(img, y,     xx - 1);
        float a12 = ldimg(img, y,     xx + 1);
        float a20 = ldimg(img, y + 1, xx - 1);
        float a21 = ldimg(img, y + 1, xx);
        float a22 = ldimg(img, y + 1, xx + 1);
        float gxv = (a00 + 2.0f * a10 + a20 - a02 - 2.0f * a12 - a22) * 0.25f;
        float gyv = (a00 + 2.0f * a01 + a02 - a20 - 2.0f * a21 - a22) * 0.25f;
        float mag = sqrtf(gxv * gxv + gyv * gyv + 1e-6f);
        ma[p] = __floats2half2_rn(mag, orient_deg(gyv, gxv));
    }
}

__device__ __forceinline__ void phaseC(const __half2* __restrict__ ma,
                                       float* __restrict__ histb, int tid) {
    for (int t = tid; t < NCELL; t += 256) {
        int base, y0, x0, ny, nx, bins;
        float invbw;                       // bins / 180
        if (t < 49) {                      // cell=4, bins=8, 4x4 px
            int cy = t / 7, cx = t - cy * 7;
            y0 = cy * 4; x0 = cx * 4; ny = 4; nx = 4;
            bins = 8; invbw = 8.0f / 180.0f;
            base = O4P + t * PB4;
        } else if (t < 130) {              // cell=3, bins=9, 3-4 x 3-4 px
            int k = t - 49;
            int cy = k / 9, cx = k - cy * 9;
            y0 = cy * 3; x0 = cx * 3;
            ny = (cy == 8) ? 4 : 3; nx = (cx == 8) ? 4 : 3;
            bins = 9; invbw = 9.0f / 180.0f;
            base = O3P + k * PB3;
        } else {                           // cell=2, bins=6, 2x2 px
            int k = t - 130;
            int cy = k / 14, cx = k - cy * 14;
            y0 = cy * 2; x0 = cx * 2; ny = 2; nx = 2;
            bins = 6; invbw = 6.0f / 180.0f;
            base = O2P + k * PB2;
        }
        for (int iy = 0; iy < ny; ++iy) {
            int row = (y0 + iy) * 28 + x0;
            for (int ix = 0; ix < nx; ++ix) {
                float2 m = __half22float2(ma[row + ix]);
                float tb = m.y * invbw;            // in [0, bins]
                int b0 = (int)tb;
                if (b0 > bins - 1) b0 = bins - 1;  // f16-edge guard
                float frac = tb - (float)b0;
                float w1 = m.x * frac;
                float w0 = m.x - w1;
                int a = base + b0;                 // b1==bins -> wrap slot
                float h0 = histb[a];
                float h1 = histb[a + 1];           // ds_read2_b32
                histb[a]     = h0 + w0;
                histb[a + 1] = h1 + w1;            // ds_write2_b32
            }
        }
        histb[base] += histb[base + bins];         // fold wrap slot
    }
}

// streaming 2-pass L2-hys norm, aligned float2 LDS reads (no reg arrays)
template <int BINS>
__device__ __forceinline__ float2 norm_task(const float* hist, int c00,
                                            int Wc, int pb) {
    int qb[4] = {c00, c00 + pb, c00 + Wc * pb, c00 + (Wc + 1) * pb};
    float s = 1e-6f;
    #pragma unroll
    for (int q = 0; q < 4; ++q) {
        #pragma unroll
        for (int j = 0; j < BINS / 2; ++j) {
            float2 v = *reinterpret_cast<const float2*>(&hist[qb[q] + 2 * j]);
            s += v.x * v.x + v.y * v.y;
        }
        if (BINS & 1) {
            float v = hist[qb[q] + BINS - 1];
            s += v * v;
        }
    }
    float ninv = 1.0f / sqrtf(s);
    float s2 = 1e-6f;
    #pragma unroll
    for (int q = 0; q < 4; ++q) {
        #pragma unroll
        for (int j = 0; j < BINS / 2; ++j) {
            float2 v = *reinterpret_cast<const float2*>(&hist[qb[q] + 2 * j]);
            float c0 = fminf(v.x * ninv, 0.2f);
            float c1 = fminf(v.y * ninv, 0.2f);
            s2 += c0 * c0 + c1 * c1;
        }
        if (BINS & 1) {
            float c = fminf(hist[qb[q] + BINS - 1] * ninv, 0.2f);
            s2 += c * c;
        }
    }
    return make_float2(ninv, 1.0f / sqrtf(s2));
}

template <bool USE_TABLE>
__device__ __forceinline__ void phaseD_flat(const float* __restrict__ histb,
                                            __half2* __restrict__ nrmb,
                                            const float* __restrict__ img,
                                            float4* __restrict__ outp,
                                            const float4* __restrict__ msr4,
                                            const float* __restrict__ fmean,
                                            const float* __restrict__ fstd,
                                            int tid) {
    for (int t = tid; t < NTASK; t += 256) {
        float2 r;
        if (t < 36) {
            int by = t / 6, bx = t - (t / 6) * 6;
            r = norm_task<8>(histb, O4P + (by * 7 + bx) * PB4, 7, PB4);
        } else if (t < 100) {
            int k = t - 36;
            r = norm_task<9>(histb, O3P + ((k >> 3) * 9 + (k & 7)) * PB3, 9, PB3);
        } else {
            int k = t - 100;
            int by = k / 13, bx = k - by * 13;
            r = norm_task<6>(histb, O2P + (by * 14 + bx) * PB2, 14, PB2);
        }
        nrmb[t] = __floats2half2_rn(r.x, r.y);
    }
    // flat part (img stable in this phase), coalesced float4 stores
    for (int i4 = tid; i4 < NPIX / 4; i4 += 256) {
        float4 v = reinterpret_cast<const float4*>(img)[i4];
        float4 r;
        if (USE_TABLE) {
            float4 p0 = msr4[i4 * 2], p1 = msr4[i4 * 2 + 1];
            r.x = (v.x - p0.x) * p0.y;  r.y = (v.y - p0.z) * p0.w;
            r.z = (v.z - p1.x) * p1.y;  r.w = (v.w - p1.z) * p1.w;
        } else {
            int i = i4 * 4;
            r.x = (v.x - fmean[i])     / fstd[i];
            r.y = (v.y - fmean[i + 1]) / fstd[i + 1];
            r.z = (v.z - fmean[i + 2]) / fstd[i + 2];
            r.w = (v.w - fmean[i + 3]) / fstd[i + 3];
        }
        outp[i4] = r;
    }
}

template <bool USE_TABLE>
__device__ __forceinline__ void ehog(const float* __restrict__ histb,
                                     const __half2* __restrict__ nrmb,
                                     float4* __restrict__ outp,
                                     const int* __restrict__ map,
                                     const float4* __restrict__ msr4,
                                     const float* __restrict__ fmean,
                                     const float* __restrict__ fstd,
                                     int tid) {
    for (int t4 = tid; t4 < NHOG / 4; t4 += 256) {
        int i4 = NPIX / 4 + t4;
        int mp[4];
        if (USE_TABLE) {
            int4 m4 = reinterpret_cast<const int4*>(map)[t4];
            mp[0] = m4.x; mp[1] = m4.y; mp[2] = m4.z; mp[3] = m4.w;
        } else {
            #pragma unroll
            for (int e = 0; e < 4; ++e) mp[e] = feat_map(i4 * 4 + e);
        }
        float2 n = __half22float2(nrmb[mp[0] >> 12]);
        float vv[4];
        #pragma unroll
        for (int e = 0; e < 4; ++e)
            vv[e] = fminf(histb[mp[e] & 4095] * n.x, 0.2f) * n.y;
        float4 r;
        if (USE_TABLE) {
            float4 p0 = msr4[i4 * 2], p1 = msr4[i4 * 2 + 1];
            r.x = (vv[0] - p0.x) * p0.y;  r.y = (vv[1] - p0.z) * p0.w;
            r.z = (vv[2] - p1.x) * p1.y;  r.w = (vv[3] - p1.z) * p1.w;
        } else {
            int i = i4 * 4;
            r.x = (vv[0] - fmean[i])     / fstd[i];
            r.y = (vv[1] - fmean[i + 1]) / fstd[i + 1];
            r.z = (vv[2] - fmean[i + 2]) / fstd[i + 2];
            r.w = (vv[3] - fmean[i + 3]) / fstd[i + 3];
        }
        outp[i4] = r;
    }
}

template <bool USE_TABLE, int NIMG>
__global__ __launch_bounds__(256)
void hog_kernel(const float* __restrict__ x,
                const float* __restrict__ fmean,
                const float* __restrict__ fstd,
                const float2* __restrict__ msr,
                const int* __restrict__ map,
                float* __restrict__ out) {
    __shared__ __align__(16) float img[NPIX];
    __shared__ __align__(16) __half2 ma[NPIX];
    __shared__ __align__(16) float hist[2][HIST_TOT];
    __shared__ __align__(16) __half2 nrm[2][NTASK];

    const int tid = threadIdx.x;
    const size_t i0 = (size_t)blockIdx.x * NIMG;
    const float4* msr4 = reinterpret_cast<const float4*>(msr);

    int p = 0;
    // ---- prologue: image 0 through phase D ----
    phaseA(x + i0 * NPIX, img, hist[0], tid);
    __syncthreads();
    phaseB(img, ma, tid);
    __syncthreads();
    phaseC(ma, hist[0], tid);
    __syncthreads();
    phaseD_flat<USE_TABLE>(hist[0], nrm[0], img,
                           reinterpret_cast<float4*>(out + i0 * FEAT),
                           msr4, fmean, fstd, tid);
    __syncthreads();

    for (int k = 0; k < NIMG; ++k) {
        float4* outk = reinterpret_cast<float4*>(out + (i0 + k) * FEAT);
        if (k + 1 < NIMG) {
            // combined phase: next image's loads + this image's coalesced
            // HOG stores (fire-and-forget; drain under B/C/D below)
            phaseA(x + (i0 + k + 1) * NPIX, img, hist[1 - p], tid);
            ehog<USE_TABLE>(hist[p], nrm[p], outk, map, msr4, fmean, fstd, tid);
            __syncthreads();
            phaseB(img, ma, tid);
            __syncthreads();
            phaseC(ma, hist[1 - p], tid);
            __syncthreads();
            phaseD_flat<USE_TABLE>(hist[1 - p], nrm[1 - p], img,
                                   reinterpret_cast<float4*>(
                                       out + (i0 + k + 1) * FEAT),
                                   msr4, fmean, fstd, tid);
            __syncthreads();
            p ^= 1;
        } else {
            ehog<USE_TABLE>(hist[p], nrm[p], outk, map, msr4, fmean, fstd, tid);
        }
    }
}

extern "C" void kernel_launch(void* const* d_in, const int* in_sizes, int n_in,
                              void* d_out, int out_size, void* d_ws, size_t ws_size,
                              hipStream_t stream) {
    const float* x     = (const float*)d_in[0];
    const float* fmean = (const float*)d_in[1];
    const float* fstd  = (const float*)d_in[2];
    float* out = (float*)d_out;
    int B = in_sizes[0] / NPIX;

    const size_t msr_bytes = (size_t)FEAT * sizeof(float2);   // 66368
    const size_t map_bytes = (size_t)NHOG * sizeof(int);      // 30048
    bool tables = ws_size >= msr_bytes + map_bytes;
    float2* msr = (float2*)d_ws;
    int* map = (int*)((char*)d_ws + msr_bytes);
    if (tables)
        hipLaunchKernelGGL(setup_kernel, dim3((FEAT + 255) / 256), dim3(256),
                           0, stream, fmean, fstd, msr, map);

    if ((B % 8) == 0) {
        if (tables)
            hipLaunchKernelGGL((hog_kernel<true, 8>), dim3(B / 8), dim3(256),
                               0, stream, x, fmean, fstd, msr, map, out);
        else
            hipLaunchKernelGGL((hog_kernel<false, 8>), dim3(B / 8), dim3(256),
                               0, stream, x, fmean, fstd, nullptr, nullptr, out);
    } else {
        if (tables)
            hipLaunchKernelGGL((hog_kernel<true, 1>), dim3(B), dim3(256),
                               0, stream, x, fmean, fstd, msr, map, out);
        else
            hipLaunchKernelGGL((hog_kernel<false, 1>), dim3(B), dim3(256),
                               0, stream, x, fmean, fstd, nullptr, nullptr, out);
    }
}

// Round 17
// 191.187 us; speedup vs baseline: 1.5399x; 1.3327x over previous
//
#include <hip/hip_runtime.h>
#include <hip/hip_fp16.h>
#include <math.h>

// HOG multi-scale feature extractor for 28x28 images. v17 (= v14/v10 + one
// minimal overlap lever): flat-part emission (196 coalesced float4 stores,
// 10% of writes) moved from phase E to right after phase A's barrier --
// img is final after A, stores are fire-and-forget and drain under B/C/D
// compute instead of the end-of-block write burst. Everything else is
// byte-identical to the reproducible 185us optimum (v10/v14): half2 ma[],
// strides (10,10,8), 19.4KB LDS (8 blocks/CU), single-nrm-per-float4
// epilogue, LDS-staged img, precomputed map/(mean,1/std) tables.

constexpr int NPIX = 784;
constexpr int FEAT = 8296;            // 784 + 1152 + 2304 + 4056
constexpr int PB4 = 10, PB3 = 10, PB2 = 8;  // padded cell strides (even)
constexpr int O4P = 0;                // 49 cells  (7x7,  8 bins)
constexpr int O3P = 490;              // 81 cells  (9x9,  9 bins)
constexpr int O2P = 1300;             // 196 cells (14x14, 6 bins)
constexpr int HIST_TOT = 2868;        // 1300 + 196*8
constexpr int NTASK = 269;            // 36 + 64 + 169 block-norm tasks
constexpr int NHOG = FEAT - NPIX;     // 7512 table entries
constexpr int NCELL = 49 + 81 + 196;  // 326 histogram cells

// ---- output index i in [784,8296) -> packed (task<<12)|hist_idx ----
__device__ __forceinline__ int feat_map(int i) {
    int task, h;
    if (i < 1936) {                    // h4: 36 tasks x 4q x 8 bins
        int k = i - 784;
        int t = k >> 5, r = k & 31;
        int q = r >> 3, j = r & 7;
        int by = t / 6, bx = t - by * 6;
        h = O4P + ((by + (q >> 1)) * 7 + bx + (q & 1)) * PB4 + j;
        task = t;
    } else if (i < 4240) {             // h3: 64 tasks x 4q x 9 bins
        int k = i - 1936;
        int t = k / 36, r = k - t * 36;
        int q = r / 9,  j = r - q * 9;
        int by = t >> 3, bx = t & 7;
        h = O3P + ((by + (q >> 1)) * 9 + bx + (q & 1)) * PB3 + j;
        task = 36 + t;
    } else {                           // h2: 169 tasks x 4q x 6 bins
        int k = i - 4240;
        int t = k / 24, r = k - t * 24;
        int q = r / 6,  j = r - q * 6;
        int by = t / 13, bx = t - by * 13;
        h = O2P + ((by + (q >> 1)) * 14 + bx + (q & 1)) * PB2 + j;
        task = 100 + t;
    }
    return (task << 12) | h;           // h < 2868 fits in 12 bits
}

__global__ __launch_bounds__(256)
void setup_kernel(const float* __restrict__ fmean,
                  const float* __restrict__ fstd,
                  float2* __restrict__ msr, int* __restrict__ map) {
    int i = blockIdx.x * 256 + threadIdx.x;
    if (i < FEAT) {
        msr[i] = make_float2(fmean[i], 1.0f / fstd[i]);
        if (i >= NPIX) map[i - NPIX] = feat_map(i);
    }
}

// branchless orientation in degrees == (atan2(gy,gx)*180/pi + 180) mod 180
__device__ __forceinline__ float orient_deg(float gy, float gx) {
    float ax = fabsf(gx), ay = fabsf(gy);
    float mn = fminf(ax, ay), mx = fmaxf(ax, ay);
    float r = __fdividef(mn, mx + 1e-37f);          // [0,1]
    float a = r * r;                                 // A&S 4.4.49, |err|<=1e-5
    float th = ((((0.0208351f * a - 0.0851330f) * a + 0.1801410f) * a
                 - 0.3302995f) * a + 0.9998660f) * r;
    th *= 57.29577951308232f;                        // rad -> deg, [0,45]
    if (ay > ax) th = 90.0f - th;                    // [0,90]
    bool neg = ((__float_as_uint(gx) ^ __float_as_uint(gy)) >> 31) != 0;
    float o = neg ? 180.0f - th : th;
    return (o >= 180.0f) ? 0.0f : o;                 // in [0,180)
}

__device__ __forceinline__ float ldimg(const float* img, int y, int x) {
    return (y >= 0 && y < 28 && x >= 0 && x < 28) ? img[y * 28 + x] : 0.0f;
}

// streaming 2-pass L2-hys norm, aligned float2 LDS reads (no reg arrays)
template <int BINS>
__device__ __forceinline__ float2 norm_task(const float* hist, int c00,
                                            int Wc, int pb) {
    int qb[4] = {c00, c00 + pb, c00 + Wc * pb, c00 + (Wc + 1) * pb};
    float s = 1e-6f;
    #pragma unroll
    for (int q = 0; q < 4; ++q) {
        #pragma unroll
        for (int j = 0; j < BINS / 2; ++j) {
            float2 v = *reinterpret_cast<const float2*>(&hist[qb[q] + 2 * j]);
            s += v.x * v.x + v.y * v.y;
        }
        if (BINS & 1) {
            float v = hist[qb[q] + BINS - 1];
            s += v * v;
        }
    }
    float ninv = 1.0f / sqrtf(s);
    float s2 = 1e-6f;
    #pragma unroll
    for (int q = 0; q < 4; ++q) {
        #pragma unroll
        for (int j = 0; j < BINS / 2; ++j) {
            float2 v = *reinterpret_cast<const float2*>(&hist[qb[q] + 2 * j]);
            float c0 = fminf(v.x * ninv, 0.2f);
            float c1 = fminf(v.y * ninv, 0.2f);
            s2 += c0 * c0 + c1 * c1;
        }
        if (BINS & 1) {
            float c = fminf(hist[qb[q] + BINS - 1] * ninv, 0.2f);
            s2 += c * c;
        }
    }
    return make_float2(ninv, 1.0f / sqrtf(s2));
}

template <bool USE_TABLE>
__global__ __launch_bounds__(256)
void hog_kernel(const float* __restrict__ x,
                const float* __restrict__ fmean,
                const float* __restrict__ fstd,
                const float2* __restrict__ msr,
                const int* __restrict__ map,
                float* __restrict__ out) {
    __shared__ __align__(16) float img[NPIX];
    __shared__ __align__(16) __half2 ma[NPIX];  // (mag, ang) packed f16
    __shared__ __align__(16) float hist[HIST_TOT];
    __shared__ float2 nrm[NTASK];

    const int b = blockIdx.x;
    const int tid = threadIdx.x;
    const float* xb = x + (size_t)b * NPIX;
    float4* outp = reinterpret_cast<float4*>(out + (size_t)b * FEAT);
    const float4* msr4 = reinterpret_cast<const float4*>(msr);

    // ---- A: load image (coalesced float4) + zero hist (float4) ----
    for (int i = tid; i < NPIX / 4; i += 256)
        reinterpret_cast<float4*>(img)[i] =
            reinterpret_cast<const float4*>(xb)[i];
    for (int i = tid; i < HIST_TOT / 4; i += 256)
        reinterpret_cast<float4*>(hist)[i] = make_float4(0.f, 0.f, 0.f, 0.f);
    __syncthreads();

    // ---- flat-part emission (img final after A): fire-and-forget stores
    //      that drain under B/C/D compute instead of the end-of-block burst
    for (int i4 = tid; i4 < NPIX / 4; i4 += 256) {
        float4 v = reinterpret_cast<const float4*>(img)[i4];
        float4 r;
        if (USE_TABLE) {
            float4 p0 = msr4[i4 * 2], p1 = msr4[i4 * 2 + 1];
            r.x = (v.x - p0.x) * p0.y;  r.y = (v.y - p0.z) * p0.w;
            r.z = (v.z - p1.x) * p1.y;  r.w = (v.w - p1.z) * p1.w;
        } else {
            int i = i4 * 4;
            r.x = (v.x - fmean[i])     / fstd[i];
            r.y = (v.y - fmean[i + 1]) / fstd[i + 1];
            r.z = (v.z - fmean[i + 2]) / fstd[i + 2];
            r.w = (v.w - fmean[i + 3]) / fstd[i + 3];
        }
        outp[i4] = r;
    }

    // ---- B: pixel-parallel Sobel + (mag, ang) -> half2 LDS ----
    for (int p = tid; p < NPIX; p += 256) {
        int y = p / 28, xx = p - (p / 28) * 28;
        float a00 = ldimg(img, y - 1, xx - 1);
        float a01 = ldimg(img, y - 1, xx);
        float a02 = ldimg(img, y - 1, xx + 1);
        float a10 = ldimg(img, y,     xx - 1);
        float a12 = ldimg(img, y,     xx + 1);
        float a20 = ldimg(img, y + 1, xx - 1);
        float a21 = ldimg(img, y + 1, xx);
        float a22 = ldimg(img, y + 1, xx + 1);
        float gxv = (a00 + 2.0f * a10 + a20 - a02 - 2.0f * a12 - a22) * 0.25f;
        float gyv = (a00 + 2.0f * a01 + a02 - a20 - 2.0f * a21 - a22) * 0.25f;
        float mag = sqrtf(gxv * gxv + gyv * gyv + 1e-6f);
        ma[p] = __floats2half2_rn(mag, orient_deg(gyv, gxv));
    }
    __syncthreads();

    // ---- C: cell-parallel exclusive RMW, wrap slot + adjacent pair.
    //      Identity task order (scale-sorted): uniform trip count per wave.
    for (int t = tid; t < NCELL; t += 256) {
        int base, y0, x0, ny, nx, bins;
        float invbw;                       // bins / 180
        if (t < 49) {                      // cell=4, bins=8, 4x4 px
            int cy = t / 7, cx = t - cy * 7;
            y0 = cy * 4; x0 = cx * 4; ny = 4; nx = 4;
            bins = 8; invbw = 8.0f / 180.0f;
            base = O4P + t * PB4;
        } else if (t < 130) {              // cell=3, bins=9, 3-4 x 3-4 px
            int k = t - 49;
            int cy = k / 9, cx = k - cy * 9;
            y0 = cy * 3; x0 = cx * 3;
            ny = (cy == 8) ? 4 : 3; nx = (cx == 8) ? 4 : 3;
            bins = 9; invbw = 9.0f / 180.0f;
            base = O3P + k * PB3;
        } else {                           // cell=2, bins=6, 2x2 px
            int k = t - 130;
            int cy = k / 14, cx = k - cy * 14;
            y0 = cy * 2; x0 = cx * 2; ny = 2; nx = 2;
            bins = 6; invbw = 6.0f / 180.0f;
            base = O2P + k * PB2;
        }
        for (int iy = 0; iy < ny; ++iy) {
            int row = (y0 + iy) * 28 + x0;
            for (int ix = 0; ix < nx; ++ix) {
                float2 m = __half22float2(ma[row + ix]);
                float tb = m.y * invbw;            // in [0, bins]
                int b0 = (int)tb;
                if (b0 > bins - 1) b0 = bins - 1;  // f16-edge guard (ang->180)
                float frac = tb - (float)b0;
                float w1 = m.x * frac;
                float w0 = m.x - w1;
                int a = base + b0;                 // b1==bins -> wrap slot
                float h0 = hist[a];
                float h1 = hist[a + 1];            // ds_read2_b32
                hist[a]     = h0 + w0;
                hist[a + 1] = h1 + w1;             // ds_write2_b32
            }
        }
        hist[base] += hist[base + bins];           // fold wrap slot into bin 0
    }
    __syncthreads();

    // ---- D: per-task L2-hys norm factors (streaming float2 reads) ----
    for (int t = tid; t < NTASK; t += 256) {
        float2 r;
        if (t < 36) {
            int by = t / 6, bx = t - (t / 6) * 6;
            r = norm_task<8>(hist, O4P + (by * 7 + bx) * PB4, 7, PB4);
        } else if (t < 100) {
            int k = t - 36;
            r = norm_task<9>(hist, O3P + ((k >> 3) * 9 + (k & 7)) * PB3, 9, PB3);
        } else {
            int k = t - 100;
            int by = k / 13, bx = k - by * 13;
            r = norm_task<6>(hist, O2P + (by * 14 + bx) * PB2, 14, PB2);
        }
        nrm[t] = r;
    }
    __syncthreads();

    // ---- E: HOG epilogue, coalesced float4 writes ----
    for (int t4 = tid; t4 < NHOG / 4; t4 += 256) {
        int i4 = NPIX / 4 + t4;
        int mp[4];
        if (USE_TABLE) {
            int4 m4 = reinterpret_cast<const int4*>(map)[t4];
            mp[0] = m4.x; mp[1] = m4.y; mp[2] = m4.z; mp[3] = m4.w;
        } else {
            #pragma unroll
            for (int e = 0; e < 4; ++e) mp[e] = feat_map(i4 * 4 + e);
        }
        // all 4 elements provably share one norm task -> single nrm read
        float2 n = nrm[mp[0] >> 12];
        float vv[4];
        #pragma unroll
        for (int e = 0; e < 4; ++e)
            vv[e] = fminf(hist[mp[e] & 4095] * n.x, 0.2f) * n.y;
        float4 r;
        if (USE_TABLE) {
            float4 p0 = msr4[i4 * 2], p1 = msr4[i4 * 2 + 1];
            r.x = (vv[0] - p0.x) * p0.y;  r.y = (vv[1] - p0.z) * p0.w;
            r.z = (vv[2] - p1.x) * p1.y;  r.w = (vv[3] - p1.z) * p1.w;
        } else {
            int i = i4 * 4;
            r.x = (vv[0] - fmean[i])     / fstd[i];
            r.y = (vv[1] - fmean[i + 1]) / fstd[i + 1];
            r.z = (vv[2] - fmean[i + 2]) / fstd[i + 2];
            r.w = (vv[3] - fmean[i + 3]) / fstd[i + 3];
        }
        outp[i4] = r;
    }
}

extern "C" void kernel_launch(void* const* d_in, const int* in_sizes, int n_in,
                              void* d_out, int out_size, void* d_ws, size_t ws_size,
                              hipStream_t stream) {
    const float* x     = (const float*)d_in[0];
    const float* fmean = (const float*)d_in[1];
    const float* fstd  = (const float*)d_in[2];
    float* out = (float*)d_out;
    int B = in_sizes[0] / NPIX;

    const size_t msr_bytes = (size_t)FEAT * sizeof(float2);   // 66368
    const size_t map_bytes = (size_t)NHOG * sizeof(int);      // 30048
    if (ws_size >= msr_bytes + map_bytes) {
        float2* msr = (float2*)d_ws;
        int* map = (int*)((char*)d_ws + msr_bytes);
        hipLaunchKernelGGL(setup_kernel, dim3((FEAT + 255) / 256), dim3(256),
                           0, stream, fmean, fstd, msr, map);
        hipLaunchKernelGGL(hog_kernel<true>, dim3(B), dim3(256), 0, stream,
                           x, fmean, fstd, msr, map, out);
    } else {
        hipLaunchKernelGGL(hog_kernel<false>, dim3(B), dim3(256), 0, stream,
                           x, fmean, fstd, nullptr, nullptr, out);
    }
}

// Round 18
// 185.419 us; speedup vs baseline: 1.5878x; 1.0311x over previous
//
#include <hip/hip_runtime.h>
#include <hip/hip_fp16.h>
#include <math.h>

// HOG multi-scale feature extractor for 28x28 images. FINAL (= v10/v14,
// measured best 185.4/185.6us, reproducible). Session summary: 721 -> 185us.
// Wins: LDS-atomic-free exclusive-ownership histogram (v4/v6), padded hist
// strides, poly-atan orientation (v3), precomputed epilogue index + msr
// tables (v3), occupancy push via half2 ma[] + tight strides -> 8 blocks/CU
// (v10), single-nrm-per-float4 epilogue (v9). All further structural edits
// (v7,v9,v11,v12,v13,v15,v16,v17) regressed: the kernel is latency-bound
// across 5 barrier-separated phases with no saturated pipe; this structure's
// empirical optimum is ~2x the pure-write roofline (~90us).

constexpr int NPIX = 784;
constexpr int FEAT = 8296;            // 784 + 1152 + 2304 + 4056
constexpr int PB4 = 10, PB3 = 10, PB2 = 8;  // padded cell strides (even)
constexpr int O4P = 0;                // 49 cells  (7x7,  8 bins)
constexpr int O3P = 490;              // 81 cells  (9x9,  9 bins)
constexpr int O2P = 1300;             // 196 cells (14x14, 6 bins)
constexpr int HIST_TOT = 2868;        // 1300 + 196*8
constexpr int NTASK = 269;            // 36 + 64 + 169 block-norm tasks
constexpr int NHOG = FEAT - NPIX;     // 7512 table entries
constexpr int NCELL = 49 + 81 + 196;  // 326 histogram cells

// ---- output index i in [784,8296) -> packed (task<<12)|hist_idx ----
__device__ __forceinline__ int feat_map(int i) {
    int task, h;
    if (i < 1936) {                    // h4: 36 tasks x 4q x 8 bins
        int k = i - 784;
        int t = k >> 5, r = k & 31;
        int q = r >> 3, j = r & 7;
        int by = t / 6, bx = t - by * 6;
        h = O4P + ((by + (q >> 1)) * 7 + bx + (q & 1)) * PB4 + j;
        task = t;
    } else if (i < 4240) {             // h3: 64 tasks x 4q x 9 bins
        int k = i - 1936;
        int t = k / 36, r = k - t * 36;
        int q = r / 9,  j = r - q * 9;
        int by = t >> 3, bx = t & 7;
        h = O3P + ((by + (q >> 1)) * 9 + bx + (q & 1)) * PB3 + j;
        task = 36 + t;
    } else {                           // h2: 169 tasks x 4q x 6 bins
        int k = i - 4240;
        int t = k / 24, r = k - t * 24;
        int q = r / 6,  j = r - q * 6;
        int by = t / 13, bx = t - by * 13;
        h = O2P + ((by + (q >> 1)) * 14 + bx + (q & 1)) * PB2 + j;
        task = 100 + t;
    }
    return (task << 12) | h;           // h < 2868 fits in 12 bits
}

__global__ __launch_bounds__(256)
void setup_kernel(const float* __restrict__ fmean,
                  const float* __restrict__ fstd,
                  float2* __restrict__ msr, int* __restrict__ map) {
    int i = blockIdx.x * 256 + threadIdx.x;
    if (i < FEAT) {
        msr[i] = make_float2(fmean[i], 1.0f / fstd[i]);
        if (i >= NPIX) map[i - NPIX] = feat_map(i);
    }
}

// branchless orientation in degrees == (atan2(gy,gx)*180/pi + 180) mod 180
__device__ __forceinline__ float orient_deg(float gy, float gx) {
    float ax = fabsf(gx), ay = fabsf(gy);
    float mn = fminf(ax, ay), mx = fmaxf(ax, ay);
    float r = __fdividef(mn, mx + 1e-37f);          // [0,1]
    float a = r * r;                                 // A&S 4.4.49, |err|<=1e-5
    float th = ((((0.0208351f * a - 0.0851330f) * a + 0.1801410f) * a
                 - 0.3302995f) * a + 0.9998660f) * r;
    th *= 57.29577951308232f;                        // rad -> deg, [0,45]
    if (ay > ax) th = 90.0f - th;                    // [0,90]
    bool neg = ((__float_as_uint(gx) ^ __float_as_uint(gy)) >> 31) != 0;
    float o = neg ? 180.0f - th : th;
    return (o >= 180.0f) ? 0.0f : o;                 // in [0,180)
}

__device__ __forceinline__ float ldimg(const float* img, int y, int x) {
    return (y >= 0 && y < 28 && x >= 0 && x < 28) ? img[y * 28 + x] : 0.0f;
}

// streaming 2-pass L2-hys norm, aligned float2 LDS reads (no reg arrays)
template <int BINS>
__device__ __forceinline__ float2 norm_task(const float* hist, int c00,
                                            int Wc, int pb) {
    int qb[4] = {c00, c00 + pb, c00 + Wc * pb, c00 + (Wc + 1) * pb};
    float s = 1e-6f;
    #pragma unroll
    for (int q = 0; q < 4; ++q) {
        #pragma unroll
        for (int j = 0; j < BINS / 2; ++j) {
            float2 v = *reinterpret_cast<const float2*>(&hist[qb[q] + 2 * j]);
            s += v.x * v.x + v.y * v.y;
        }
        if (BINS & 1) {
            float v = hist[qb[q] + BINS - 1];
            s += v * v;
        }
    }
    float ninv = 1.0f / sqrtf(s);
    float s2 = 1e-6f;
    #pragma unroll
    for (int q = 0; q < 4; ++q) {
        #pragma unroll
        for (int j = 0; j < BINS / 2; ++j) {
            float2 v = *reinterpret_cast<const float2*>(&hist[qb[q] + 2 * j]);
            float c0 = fminf(v.x * ninv, 0.2f);
            float c1 = fminf(v.y * ninv, 0.2f);
            s2 += c0 * c0 + c1 * c1;
        }
        if (BINS & 1) {
            float c = fminf(hist[qb[q] + BINS - 1] * ninv, 0.2f);
            s2 += c * c;
        }
    }
    return make_float2(ninv, 1.0f / sqrtf(s2));
}

template <bool USE_TABLE>
__global__ __launch_bounds__(256)
void hog_kernel(const float* __restrict__ x,
                const float* __restrict__ fmean,
                const float* __restrict__ fstd,
                const float2* __restrict__ msr,
                const int* __restrict__ map,
                float* __restrict__ out) {
    __shared__ __align__(16) float img[NPIX];
    __shared__ __align__(16) __half2 ma[NPIX];  // (mag, ang) packed f16
    __shared__ __align__(16) float hist[HIST_TOT];
    __shared__ float2 nrm[NTASK];

    const int b = blockIdx.x;
    const int tid = threadIdx.x;
    const float* xb = x + (size_t)b * NPIX;

    // ---- A: load image (coalesced float4) + zero hist (float4) ----
    for (int i = tid; i < NPIX / 4; i += 256)
        reinterpret_cast<float4*>(img)[i] =
            reinterpret_cast<const float4*>(xb)[i];
    for (int i = tid; i < HIST_TOT / 4; i += 256)
        reinterpret_cast<float4*>(hist)[i] = make_float4(0.f, 0.f, 0.f, 0.f);
    __syncthreads();

    // ---- B: pixel-parallel Sobel + (mag, ang) -> half2 LDS ----
    for (int p = tid; p < NPIX; p += 256) {
        int y = p / 28, xx = p - (p / 28) * 28;
        float a00 = ldimg(img, y - 1, xx - 1);
        float a01 = ldimg(img, y - 1, xx);
        float a02 = ldimg(img, y - 1, xx + 1);
        float a10 = ldimg(img, y,     xx - 1);
        float a12 = ldimg(img, y,     xx + 1);
        float a20 = ldimg(img, y + 1, xx - 1);
        float a21 = ldimg(img, y + 1, xx);
        float a22 = ldimg(img, y + 1, xx + 1);
        float gxv = (a00 + 2.0f * a10 + a20 - a02 - 2.0f * a12 - a22) * 0.25f;
        float gyv = (a00 + 2.0f * a01 + a02 - a20 - 2.0f * a21 - a22) * 0.25f;
        float mag = sqrtf(gxv * gxv + gyv * gyv + 1e-6f);
        ma[p] = __floats2half2_rn(mag, orient_deg(gyv, gxv));
    }
    __syncthreads();

    // ---- C: cell-parallel exclusive RMW, wrap slot + adjacent pair.
    //      Identity task order (scale-sorted): uniform trip count per wave.
    for (int t = tid; t < NCELL; t += 256) {
        int base, y0, x0, ny, nx, bins;
        float invbw;                       // bins / 180
        if (t < 49) {                      // cell=4, bins=8, 4x4 px
            int cy = t / 7, cx = t - cy * 7;
            y0 = cy * 4; x0 = cx * 4; ny = 4; nx = 4;
            bins = 8; invbw = 8.0f / 180.0f;
            base = O4P + t * PB4;
        } else if (t < 130) {              // cell=3, bins=9, 3-4 x 3-4 px
            int k = t - 49;
            int cy = k / 9, cx = k - cy * 9;
            y0 = cy * 3; x0 = cx * 3;
            ny = (cy == 8) ? 4 : 3; nx = (cx == 8) ? 4 : 3;
            bins = 9; invbw = 9.0f / 180.0f;
            base = O3P + k * PB3;
        } else {                           // cell=2, bins=6, 2x2 px
            int k = t - 130;
            int cy = k / 14, cx = k - cy * 14;
            y0 = cy * 2; x0 = cx * 2; ny = 2; nx = 2;
            bins = 6; invbw = 6.0f / 180.0f;
            base = O2P + k * PB2;
        }
        for (int iy = 0; iy < ny; ++iy) {
            int row = (y0 + iy) * 28 + x0;
            for (int ix = 0; ix < nx; ++ix) {
                float2 m = __half22float2(ma[row + ix]);
                float tb = m.y * invbw;            // in [0, bins]
                int b0 = (int)tb;
                if (b0 > bins - 1) b0 = bins - 1;  // f16-edge guard (ang->180)
                float frac = tb - (float)b0;
                float w1 = m.x * frac;
                float w0 = m.x - w1;
                int a = base + b0;                 // b1==bins -> wrap slot
                float h0 = hist[a];
                float h1 = hist[a + 1];            // ds_read2_b32
                hist[a]     = h0 + w0;
                hist[a + 1] = h1 + w1;             // ds_write2_b32
            }
        }
        hist[base] += hist[base + bins];           // fold wrap slot into bin 0
    }
    __syncthreads();

    // ---- D: per-task L2-hys norm factors (streaming float2 reads) ----
    for (int t = tid; t < NTASK; t += 256) {
        float2 r;
        if (t < 36) {
            int by = t / 6, bx = t - (t / 6) * 6;
            r = norm_task<8>(hist, O4P + (by * 7 + bx) * PB4, 7, PB4);
        } else if (t < 100) {
            int k = t - 36;
            r = norm_task<9>(hist, O3P + ((k >> 3) * 9 + (k & 7)) * PB3, 9, PB3);
        } else {
            int k = t - 100;
            int by = k / 13, bx = k - by * 13;
            r = norm_task<6>(hist, O2P + (by * 14 + bx) * PB2, 14, PB2);
        }
        nrm[t] = r;
    }
    __syncthreads();

    // ---- E: epilogue, coalesced float4 writes ----
    float4* outp = reinterpret_cast<float4*>(out + (size_t)b * FEAT);

    for (int i4 = tid; i4 < NPIX / 4; i4 += 256) {
        float4 v = reinterpret_cast<const float4*>(img)[i4];
        float4 r;
        if (USE_TABLE) {
            const float4* msr4 = reinterpret_cast<const float4*>(msr);
            float4 p0 = msr4[i4 * 2], p1 = msr4[i4 * 2 + 1];
            r.x = (v.x - p0.x) * p0.y;  r.y = (v.y - p0.z) * p0.w;
            r.z = (v.z - p1.x) * p1.y;  r.w = (v.w - p1.z) * p1.w;
        } else {
            int i = i4 * 4;
            r.x = (v.x - fmean[i])     / fstd[i];
            r.y = (v.y - fmean[i + 1]) / fstd[i + 1];
            r.z = (v.z - fmean[i + 2]) / fstd[i + 2];
            r.w = (v.w - fmean[i + 3]) / fstd[i + 3];
        }
        outp[i4] = r;
    }

    for (int t4 = tid; t4 < NHOG / 4; t4 += 256) {
        int i4 = NPIX / 4 + t4;
        int mp[4];
        if (USE_TABLE) {
            int4 m4 = reinterpret_cast<const int4*>(map)[t4];
            mp[0] = m4.x; mp[1] = m4.y; mp[2] = m4.z; mp[3] = m4.w;
        } else {
            #pragma unroll
            for (int e = 0; e < 4; ++e) mp[e] = feat_map(i4 * 4 + e);
        }
        // all 4 elements provably share one norm task -> single nrm read
        float2 n = nrm[mp[0] >> 12];
        float vv[4];
        #pragma unroll
        for (int e = 0; e < 4; ++e)
            vv[e] = fminf(hist[mp[e] & 4095] * n.x, 0.2f) * n.y;
        float4 r;
        if (USE_TABLE) {
            const float4* msr4 = reinterpret_cast<const float4*>(msr);
            float4 p0 = msr4[i4 * 2], p1 = msr4[i4 * 2 + 1];
            r.x = (vv[0] - p0.x) * p0.y;  r.y = (vv[1] - p0.z) * p0.w;
            r.z = (vv[2] - p1.x) * p1.y;  r.w = (vv[3] - p1.z) * p1.w;
        } else {
            int i = i4 * 4;
            r.x = (vv[0] - fmean[i])     / fstd[i];
            r.y = (vv[1] - fmean[i + 1]) / fstd[i + 1];
            r.z = (vv[2] - fmean[i + 2]) / fstd[i + 2];
            r.w = (vv[3] - fmean[i + 3]) / fstd[i + 3];
        }
        outp[i4] = r;
    }
}

extern "C" void kernel_launch(void* const* d_in, const int* in_sizes, int n_in,
                              void* d_out, int out_size, void* d_ws, size_t ws_size,
                              hipStream_t stream) {
    const float* x     = (const float*)d_in[0];
    const float* fmean = (const float*)d_in[1];
    const float* fstd  = (const float*)d_in[2];
    float* out = (float*)d_out;
    int B = in_sizes[0] / NPIX;

    const size_t msr_bytes = (size_t)FEAT * sizeof(float2);   // 66368
    const size_t map_bytes = (size_t)NHOG * sizeof(int);      // 30048
    if (ws_size >= msr_bytes + map_bytes) {
        float2* msr = (float2*)d_ws;
        int* map = (int*)((char*)d_ws + msr_bytes);
        hipLaunchKernelGGL(setup_kernel, dim3((FEAT + 255) / 256), dim3(256),
                           0, stream, fmean, fstd, msr, map);
        hipLaunchKernelGGL(hog_kernel<true>, dim3(B), dim3(256), 0, stream,
                           x, fmean, fstd, msr, map, out);
    } else {
        hipLaunchKernelGGL(hog_kernel<false>, dim3(B), dim3(256), 0, stream,
                           x, fmean, fstd, nullptr, nullptr, out);
    }
}